// Round 6
// baseline (5406.887 us; speedup 1.0000x reference)
//
#include <hip/hip_runtime.h>
#include <hip/hip_fp16.h>

typedef _Float16 h2 __attribute__((ext_vector_type(2)));
typedef _Float16 h8 __attribute__((ext_vector_type(8)));
typedef float f4 __attribute__((ext_vector_type(4)));
typedef unsigned int uv16 __attribute__((ext_vector_type(16)));

static constexpr int TT = 2048;
static constexpr int BB = 64;
static constexpr int II = 256;
static constexpr int HH = 256;
static constexpr int G3 = 768;   // 3*H

static __device__ __forceinline__ unsigned int pk2(float a, float b) {
    return __builtin_bit_cast(unsigned int, __builtin_amdgcn_cvt_pkrtz(a, b));
}
static __device__ __forceinline__ float fdot2u(unsigned int w, unsigned int h, float acc) {
    return __builtin_amdgcn_fdot2(__builtin_bit_cast(h2, w), __builtin_bit_cast(h2, h), acc, false);
}
template <int OFF>
static __device__ __forceinline__ float swz_add(float s) {
    int v = __builtin_amdgcn_ds_swizzle(__builtin_bit_cast(int, s), OFF);
    return s + __builtin_bit_cast(float, v);
}

// ---------------------------------------------------------------------------
// Kernel 0: cast W_ih fp32 -> fp16 (tiny, one-time)
// ---------------------------------------------------------------------------
__global__ void cast_wih(const float* __restrict__ w, _Float16* __restrict__ o, int n) {
    int i = blockIdx.x * blockDim.x + threadIdx.x;
    if (i < n) o[i] = (_Float16)w[i];
}

// ---------------------------------------------------------------------------
// Kernel 1: gi = x @ W_ih^T + b_ih, stored fp16 [B*T][768]
// Per-wave 64x64 C tile, K=256, no LDS. MFMA f32_16x16x32_f16.
// ---------------------------------------------------------------------------
__global__ void gi_gemm(const float* __restrict__ x, const _Float16* __restrict__ wih,
                        const float* __restrict__ bih, _Float16* __restrict__ gi) {
    const int lane = threadIdx.x & 63;
    const int wid  = threadIdx.x >> 6;
    const int gt   = blockIdx.x * 4 + wid;       // wave-tile id, n fastest
    const int nt   = gt % 12;
    const int mt   = gt / 12;
    const int m0   = mt * 64;
    const int n0   = nt * 64;
    const int lr   = lane & 15;
    const int kg   = (lane >> 4) * 8;

    f4 acc[4][4] = {};

    #pragma unroll
    for (int kk = 0; kk < 256; kk += 32) {
        h8 af[4];
        h8 bf[4];
        #pragma unroll
        for (int m = 0; m < 4; ++m) {
            const float* ap = x + (size_t)(m0 + m * 16 + lr) * 256 + kk + kg;
            f4 lo = *(const f4*)ap;
            f4 hi = *(const f4*)(ap + 4);
            uint4 uu;
            uu.x = pk2(lo.x, lo.y);
            uu.y = pk2(lo.z, lo.w);
            uu.z = pk2(hi.x, hi.y);
            uu.w = pk2(hi.z, hi.w);
            af[m] = __builtin_bit_cast(h8, uu);
        }
        #pragma unroll
        for (int n = 0; n < 4; ++n) {
            bf[n] = *(const h8*)(wih + (size_t)(n0 + n * 16 + lr) * 256 + kk + kg);
        }
        #pragma unroll
        for (int m = 0; m < 4; ++m) {
            #pragma unroll
            for (int n = 0; n < 4; ++n) {
                acc[m][n] = __builtin_amdgcn_mfma_f32_16x16x32_f16(af[m], bf[n], acc[m][n], 0, 0, 0);
            }
        }
    }

    const int rg = (lane >> 4) * 4;
    #pragma unroll
    for (int n = 0; n < 4; ++n) {
        const int col = n0 + n * 16 + lr;
        const float bv = bih[col];
        #pragma unroll
        for (int m = 0; m < 4; ++m) {
            #pragma unroll
            for (int r = 0; r < 4; ++r) {
                const int row = m0 + m * 16 + rg + r;
                gi[(size_t)row * G3 + col] = (_Float16)(acc[m][n][r] + bv);
            }
        }
    }
}

// ---------------------------------------------------------------------------
// Kernel 2: sequential GRU scan. One workgroup per batch element.
// 768 threads = (rgrp = tid>>3) x (sub = tid&7). Thread owns rows
// rgrp*8 + j (j=0..7), columns [sub*32, sub*32+32) of W_hh: 8 x 16 packed
// f16x2 = 128 uints as named SSA uv16 values (compile-time indices only).
// Per step: read 64B h slice (4 x b128), 8 rows x 16 fdot2, 8-lane
// ds_swizzle butterfly per row, gate math in threads 0..255 (h in reg).
// NOTE: n-gate bias is r-gated: n = tanh(i_n + r*(dot_n + b_hn)).
// ---------------------------------------------------------------------------
__global__ __launch_bounds__(768) void gru_scan(
        const _Float16* __restrict__ gi, const float* __restrict__ whh,
        const float* __restrict__ bhh, float* __restrict__ out) {
    __shared__ alignas(16) unsigned int hpk[128];  // h as packed f16x2
    __shared__ float ghl[768];                     // raw h-side dot sums

    const int b    = blockIdx.x;
    const int tid  = threadIdx.x;
    const int sub  = tid & 7;
    const int rbase = (tid >> 3) * 8;

    auto loadrow = [&](int j) -> uv16 {
        const f4* wp = (const f4*)(whh + (size_t)(rbase + j) * 256 + sub * 32);
        uv16 W;
        #pragma unroll
        for (int i = 0; i < 8; ++i) {
            f4 v = wp[i];
            W[2 * i]     = pk2(v.x, v.y);
            W[2 * i + 1] = pk2(v.z, v.w);
        }
        return W;
    };
    const uv16 w0 = loadrow(0), w1 = loadrow(1), w2 = loadrow(2), w3 = loadrow(3),
               w4 = loadrow(4), w5 = loadrow(5), w6 = loadrow(6), w7 = loadrow(7);

    if (tid < 128) hpk[tid] = 0u;

    // gate-math threads: bias + 2-deep gi prefetch
    const _Float16* gb = gi + (size_t)b * TT * G3;
    float b_r = 0.f, b_z = 0.f, b_n = 0.f;
    float c_r = 0.f, c_z = 0.f, c_n = 0.f;   // step t
    float n_r = 0.f, n_z = 0.f, n_n = 0.f;   // step t+1
    float hcur = 0.f;
    if (tid < 256) {
        b_r = bhh[tid];
        b_z = bhh[256 + tid];
        b_n = bhh[512 + tid];
        c_r = (float)gb[tid];
        c_z = (float)gb[256 + tid];
        c_n = (float)gb[512 + tid];
        n_r = (float)gb[G3 + tid];
        n_z = (float)gb[G3 + 256 + tid];
        n_n = (float)gb[G3 + 512 + tid];
    }
    __syncthreads();

    for (int t = 0; t < TT; ++t) {
        // issue loads for step t+2 (consumed ~2 steps later)
        float p_r = 0.f, p_z = 0.f, p_n = 0.f;
        if (tid < 256 && t + 2 < TT) {
            const _Float16* g2 = gb + (size_t)(t + 2) * G3;
            p_r = (float)g2[tid];
            p_z = (float)g2[256 + tid];
            p_n = (float)g2[512 + tid];
        }

        // this thread's h slice: h[sub*32 .. sub*32+31] as 16 packed uints
        const uint4* hp = (const uint4*)&hpk[sub * 16];
        const uint4 hq0 = hp[0], hq1 = hp[1], hq2 = hp[2], hq3 = hp[3];

        auto dotrow = [&](uv16 W) -> float {
            float a0 = 0.f, a1 = 0.f, a2 = 0.f, a3 = 0.f;
            a0 = fdot2u(W[0],  hq0.x, a0); a1 = fdot2u(W[1],  hq0.y, a1);
            a2 = fdot2u(W[2],  hq0.z, a2); a3 = fdot2u(W[3],  hq0.w, a3);
            a0 = fdot2u(W[4],  hq1.x, a0); a1 = fdot2u(W[5],  hq1.y, a1);
            a2 = fdot2u(W[6],  hq1.z, a2); a3 = fdot2u(W[7],  hq1.w, a3);
            a0 = fdot2u(W[8],  hq2.x, a0); a1 = fdot2u(W[9],  hq2.y, a1);
            a2 = fdot2u(W[10], hq2.z, a2); a3 = fdot2u(W[11], hq2.w, a3);
            a0 = fdot2u(W[12], hq3.x, a0); a1 = fdot2u(W[13], hq3.y, a1);
            a2 = fdot2u(W[14], hq3.z, a2); a3 = fdot2u(W[15], hq3.w, a3);
            return (a0 + a1) + (a2 + a3);
        };
        float s0 = dotrow(w0), s1 = dotrow(w1), s2 = dotrow(w2), s3 = dotrow(w3),
              s4 = dotrow(w4), s5 = dotrow(w5), s6 = dotrow(w6), s7 = dotrow(w7);

        // 8-lane butterfly allreduce per row (BitMode: xor<<10 | and 0x1F)
        #define RED(S) S = swz_add<0x041F>(S); S = swz_add<0x081F>(S); S = swz_add<0x101F>(S);
        RED(s0) RED(s1) RED(s2) RED(s3) RED(s4) RED(s5) RED(s6) RED(s7)
        #undef RED

        if (sub == 0) {
            ghl[rbase + 0] = s0; ghl[rbase + 1] = s1;
            ghl[rbase + 2] = s2; ghl[rbase + 3] = s3;
            ghl[rbase + 4] = s4; ghl[rbase + 5] = s5;
            ghl[rbase + 6] = s6; ghl[rbase + 7] = s7;
        }
        __syncthreads();

        if (tid < 256) {
            const float xr = c_r + b_r + ghl[tid];
            const float xz = c_z + b_z + ghl[256 + tid];
            const float r = __builtin_amdgcn_rcpf(1.f + __expf(-xr));
            const float z = __builtin_amdgcn_rcpf(1.f + __expf(-xz));
            // b_hn must be r-gated: n = tanh(i_n + r*(dot_n + b_hn))
            const float xn = c_n + r * (ghl[512 + tid] + b_n);
            const float th = 1.f - 2.f * __builtin_amdgcn_rcpf(__expf(2.f * xn) + 1.f);
            hcur = (1.f - z) * th + z * hcur;
            ((_Float16*)hpk)[tid] = (_Float16)hcur;
            c_r = n_r; c_z = n_z; c_n = n_n;
            n_r = p_r; n_z = p_z; n_n = p_n;
        }
        __syncthreads();
    }

    if (tid < 256) out[(size_t)b * HH + tid] = hcur;
}

// ---------------------------------------------------------------------------
extern "C" void kernel_launch(void* const* d_in, const int* in_sizes, int n_in,
                              void* d_out, int out_size, void* d_ws, size_t ws_size,
                              hipStream_t stream) {
    const float* x   = (const float*)d_in[0];
    const float* wih = (const float*)d_in[1];
    const float* whh = (const float*)d_in[2];
    const float* bih = (const float*)d_in[3];
    const float* bhh = (const float*)d_in[4];
    float* out = (float*)d_out;

    // workspace: [0, 384KB) W_ih fp16 ; [512KB, 512KB+192MB) gi fp16
    _Float16* wih_h = (_Float16*)d_ws;
    _Float16* gi    = (_Float16*)((char*)d_ws + 512 * 1024);

    cast_wih<<<768, 256, 0, stream>>>(wih, wih_h, G3 * II);
    gi_gemm<<<6144, 256, 0, stream>>>(x, wih_h, bih, gi);
    gru_scan<<<BB, 768, 0, stream>>>(gi, whh, bhh, out);
}

// Round 7
// 3248.664 us; speedup vs baseline: 1.6643x; 1.6643x over previous
//
#include <hip/hip_runtime.h>
#include <hip/hip_fp16.h>

typedef _Float16 h2 __attribute__((ext_vector_type(2)));
typedef _Float16 h8 __attribute__((ext_vector_type(8)));
typedef float f4 __attribute__((ext_vector_type(4)));
typedef unsigned int uv16 __attribute__((ext_vector_type(16)));

static constexpr int TT = 2048;
static constexpr int BB = 64;
static constexpr int II = 256;
static constexpr int HH = 256;
static constexpr int G3 = 768;   // 3*H

static __device__ __forceinline__ unsigned int pk2(float a, float b) {
    return __builtin_bit_cast(unsigned int, __builtin_amdgcn_cvt_pkrtz(a, b));
}
static __device__ __forceinline__ float fdot2u(unsigned int w, unsigned int h, float acc) {
    return __builtin_amdgcn_fdot2(__builtin_bit_cast(h2, w), __builtin_bit_cast(h2, h), acc, false);
}
template <int OFF>
static __device__ __forceinline__ float swz_add(float s) {
    int v = __builtin_amdgcn_ds_swizzle(__builtin_bit_cast(int, s), OFF);
    return s + __builtin_bit_cast(float, v);
}
// 16 fdot2 of one uv16 weight block against 16 packed h uints
static __device__ __forceinline__ float dot16(uv16 W, uint4 A, uint4 B, uint4 C, uint4 D, float s) {
    float a0 = 0.f, a1 = 0.f, a2 = 0.f, a3 = 0.f;
    a0 = fdot2u(W[0],  A.x, a0); a1 = fdot2u(W[1],  A.y, a1);
    a2 = fdot2u(W[2],  A.z, a2); a3 = fdot2u(W[3],  A.w, a3);
    a0 = fdot2u(W[4],  B.x, a0); a1 = fdot2u(W[5],  B.y, a1);
    a2 = fdot2u(W[6],  B.z, a2); a3 = fdot2u(W[7],  B.w, a3);
    a0 = fdot2u(W[8],  C.x, a0); a1 = fdot2u(W[9],  C.y, a1);
    a2 = fdot2u(W[10], C.z, a2); a3 = fdot2u(W[11], C.w, a3);
    a0 = fdot2u(W[12], D.x, a0); a1 = fdot2u(W[13], D.y, a1);
    a2 = fdot2u(W[14], D.z, a2); a3 = fdot2u(W[15], D.w, a3);
    return s + ((a0 + a1) + (a2 + a3));
}

// ---------------------------------------------------------------------------
// Kernel 0: cast W_ih fp32 -> fp16 (tiny, one-time)
// ---------------------------------------------------------------------------
__global__ void cast_wih(const float* __restrict__ w, _Float16* __restrict__ o, int n) {
    int i = blockIdx.x * blockDim.x + threadIdx.x;
    if (i < n) o[i] = (_Float16)w[i];
}

// ---------------------------------------------------------------------------
// Kernel 1: gi = x @ W_ih^T + b_ih, stored fp16 [B*T][768]
// Per-wave 64x64 C tile, K=256, no LDS. MFMA f32_16x16x32_f16.
// ---------------------------------------------------------------------------
__global__ void gi_gemm(const float* __restrict__ x, const _Float16* __restrict__ wih,
                        const float* __restrict__ bih, _Float16* __restrict__ gi) {
    const int lane = threadIdx.x & 63;
    const int wid  = threadIdx.x >> 6;
    const int gt   = blockIdx.x * 4 + wid;       // wave-tile id, n fastest
    const int nt   = gt % 12;
    const int mt   = gt / 12;
    const int m0   = mt * 64;
    const int n0   = nt * 64;
    const int lr   = lane & 15;
    const int kg   = (lane >> 4) * 8;

    f4 acc[4][4] = {};

    #pragma unroll
    for (int kk = 0; kk < 256; kk += 32) {
        h8 af[4];
        h8 bf[4];
        #pragma unroll
        for (int m = 0; m < 4; ++m) {
            const float* ap = x + (size_t)(m0 + m * 16 + lr) * 256 + kk + kg;
            f4 lo = *(const f4*)ap;
            f4 hi = *(const f4*)(ap + 4);
            uint4 uu;
            uu.x = pk2(lo.x, lo.y);
            uu.y = pk2(lo.z, lo.w);
            uu.z = pk2(hi.x, hi.y);
            uu.w = pk2(hi.z, hi.w);
            af[m] = __builtin_bit_cast(h8, uu);
        }
        #pragma unroll
        for (int n = 0; n < 4; ++n) {
            bf[n] = *(const h8*)(wih + (size_t)(n0 + n * 16 + lr) * 256 + kk + kg);
        }
        #pragma unroll
        for (int m = 0; m < 4; ++m) {
            #pragma unroll
            for (int n = 0; n < 4; ++n) {
                acc[m][n] = __builtin_amdgcn_mfma_f32_16x16x32_f16(af[m], bf[n], acc[m][n], 0, 0, 0);
            }
        }
    }

    const int rg = (lane >> 4) * 4;
    #pragma unroll
    for (int n = 0; n < 4; ++n) {
        const int col = n0 + n * 16 + lr;
        const float bv = bih[col];
        #pragma unroll
        for (int m = 0; m < 4; ++m) {
            #pragma unroll
            for (int r = 0; r < 4; ++r) {
                const int row = m0 + m * 16 + rg + r;
                gi[(size_t)row * G3 + col] = (_Float16)(acc[m][n][r] + bv);
            }
        }
    }
}

// ---------------------------------------------------------------------------
// Kernel 2: sequential GRU scan. One workgroup per batch element.
// 512 threads = (rgrp = tid>>1) x (sub = tid&1). Thread owns rows
// rgrp*3 + j (j=0..2), columns [sub*128, sub*128+128) of W_hh:
// 3 x 4 uv16 = 192 packed-f16x2 regs as named SSA values. 8 waves =
// 2 waves/SIMD -> 256-VGPR cap; amdgpu_waves_per_eu(2,2) pins the
// allocator there (the 768-thread versions spilled at cap 170).
// Per step: 4 q-blocks of {4 x b128 h-read, 3 rows x 16 fdot2},
// 2-lane ds_swizzle reduce, gate math in threads 0..255 (h in reg).
// n-gate bias is r-gated: n = tanh(i_n + r*(dot_n + b_hn)).
// ---------------------------------------------------------------------------
__global__ __launch_bounds__(512)
__attribute__((amdgpu_waves_per_eu(2, 2)))
void gru_scan(
        const _Float16* __restrict__ gi, const float* __restrict__ whh,
        const float* __restrict__ bhh, float* __restrict__ out) {
    __shared__ alignas(16) unsigned int hpk[128];  // h as packed f16x2
    __shared__ float ghl[768];                     // raw h-side dot sums

    const int b     = blockIdx.x;
    const int tid   = threadIdx.x;
    const int sub   = tid & 1;
    const int rbase = (tid >> 1) * 3;

    auto loadw = [&](int j, int q) -> uv16 {
        const f4* wp = (const f4*)(whh + (size_t)(rbase + j) * 256 + sub * 128 + q * 32);
        uv16 W;
        #pragma unroll
        for (int i = 0; i < 8; ++i) {
            f4 v = wp[i];
            W[2 * i]     = pk2(v.x, v.y);
            W[2 * i + 1] = pk2(v.z, v.w);
        }
        return W;
    };
    const uv16 w00 = loadw(0,0), w01 = loadw(0,1), w02 = loadw(0,2), w03 = loadw(0,3);
    const uv16 w10 = loadw(1,0), w11 = loadw(1,1), w12 = loadw(1,2), w13 = loadw(1,3);
    const uv16 w20 = loadw(2,0), w21 = loadw(2,1), w22 = loadw(2,2), w23 = loadw(2,3);

    if (tid < 128) hpk[tid] = 0u;

    // gate-math threads: bias + 2-deep gi prefetch
    const _Float16* gb = gi + (size_t)b * TT * G3;
    float b_r = 0.f, b_z = 0.f, b_n = 0.f;
    float c_r = 0.f, c_z = 0.f, c_n = 0.f;   // step t
    float n_r = 0.f, n_z = 0.f, n_n = 0.f;   // step t+1
    float hcur = 0.f;
    if (tid < 256) {
        b_r = bhh[tid];
        b_z = bhh[256 + tid];
        b_n = bhh[512 + tid];
        c_r = (float)gb[tid];
        c_z = (float)gb[256 + tid];
        c_n = (float)gb[512 + tid];
        n_r = (float)gb[G3 + tid];
        n_z = (float)gb[G3 + 256 + tid];
        n_n = (float)gb[G3 + 512 + tid];
    }
    __syncthreads();

    for (int t = 0; t < TT; ++t) {
        // issue loads for step t+2 (consumed ~2 steps later)
        float p_r = 0.f, p_z = 0.f, p_n = 0.f;
        if (tid < 256 && t + 2 < TT) {
            const _Float16* g2 = gb + (size_t)(t + 2) * G3;
            p_r = (float)g2[tid];
            p_z = (float)g2[256 + tid];
            p_n = (float)g2[512 + tid];
        }

        float s0 = 0.f, s1 = 0.f, s2 = 0.f;
        #define QBLOCK(q, W0, W1, W2)                                         \
        {                                                                     \
            const uint4* hp = (const uint4*)&hpk[sub * 64 + (q) * 16];        \
            const uint4 A = hp[0], B = hp[1], C = hp[2], D = hp[3];           \
            s0 = dot16(W0, A, B, C, D, s0);                                   \
            s1 = dot16(W1, A, B, C, D, s1);                                   \
            s2 = dot16(W2, A, B, C, D, s2);                                   \
        }
        QBLOCK(0, w00, w10, w20)
        QBLOCK(1, w01, w11, w21)
        QBLOCK(2, w02, w12, w22)
        QBLOCK(3, w03, w13, w23)
        #undef QBLOCK

        // 2-lane butterfly (xor 1) reduces the two column halves
        s0 = swz_add<0x041F>(s0);
        s1 = swz_add<0x041F>(s1);
        s2 = swz_add<0x041F>(s2);
        if (sub == 0) {
            ghl[rbase + 0] = s0;
            ghl[rbase + 1] = s1;
            ghl[rbase + 2] = s2;
        }
        __syncthreads();

        if (tid < 256) {
            const float xr = c_r + b_r + ghl[tid];
            const float xz = c_z + b_z + ghl[256 + tid];
            const float r = __builtin_amdgcn_rcpf(1.f + __expf(-xr));
            const float z = __builtin_amdgcn_rcpf(1.f + __expf(-xz));
            // b_hn must be r-gated: n = tanh(i_n + r*(dot_n + b_hn))
            const float xn = c_n + r * (ghl[512 + tid] + b_n);
            const float th = 1.f - 2.f * __builtin_amdgcn_rcpf(__expf(2.f * xn) + 1.f);
            hcur = (1.f - z) * th + z * hcur;
            ((_Float16*)hpk)[tid] = (_Float16)hcur;
            c_r = n_r; c_z = n_z; c_n = n_n;
            n_r = p_r; n_z = p_z; n_n = p_n;
        }
        __syncthreads();
    }

    if (tid < 256) out[(size_t)b * HH + tid] = hcur;
}

// ---------------------------------------------------------------------------
extern "C" void kernel_launch(void* const* d_in, const int* in_sizes, int n_in,
                              void* d_out, int out_size, void* d_ws, size_t ws_size,
                              hipStream_t stream) {
    const float* x   = (const float*)d_in[0];
    const float* wih = (const float*)d_in[1];
    const float* whh = (const float*)d_in[2];
    const float* bih = (const float*)d_in[3];
    const float* bhh = (const float*)d_in[4];
    float* out = (float*)d_out;

    // workspace: [0, 384KB) W_ih fp16 ; [512KB, 512KB+192MB) gi fp16
    _Float16* wih_h = (_Float16*)d_ws;
    _Float16* gi    = (_Float16*)((char*)d_ws + 512 * 1024);

    cast_wih<<<768, 256, 0, stream>>>(wih, wih_h, G3 * II);
    gi_gemm<<<6144, 256, 0, stream>>>(x, wih_h, bih, gi);
    gru_scan<<<BB, 512, 0, stream>>>(gi, whh, bhh, out);
}

// Round 8
// 3234.846 us; speedup vs baseline: 1.6715x; 1.0043x over previous
//
#include <hip/hip_runtime.h>
#include <hip/hip_fp16.h>

typedef _Float16 h2 __attribute__((ext_vector_type(2)));
typedef _Float16 h8 __attribute__((ext_vector_type(8)));
typedef float f4 __attribute__((ext_vector_type(4)));
typedef unsigned int uv16 __attribute__((ext_vector_type(16)));

static constexpr int TT = 2048;
static constexpr int BB = 64;
static constexpr int II = 256;
static constexpr int HH = 256;
static constexpr int G3 = 768;   // 3*H

static __device__ __forceinline__ unsigned int pk2(float a, float b) {
    return __builtin_bit_cast(unsigned int, __builtin_amdgcn_cvt_pkrtz(a, b));
}
static __device__ __forceinline__ float fdot2u(unsigned int w, unsigned int h, float acc) {
    return __builtin_amdgcn_fdot2(__builtin_bit_cast(h2, w), __builtin_bit_cast(h2, h), acc, false);
}
template <int OFF>
static __device__ __forceinline__ float swz_add(float s) {
    int v = __builtin_amdgcn_ds_swizzle(__builtin_bit_cast(int, s), OFF);
    return s + __builtin_bit_cast(float, v);
}
// 16 fdot2 of one uv16 weight block against 16 packed h uints
static __device__ __forceinline__ float dot16(uv16 W, uint4 A, uint4 B, uint4 C, uint4 D, float s) {
    float a0 = 0.f, a1 = 0.f, a2 = 0.f, a3 = 0.f;
    a0 = fdot2u(W[0],  A.x, a0); a1 = fdot2u(W[1],  A.y, a1);
    a2 = fdot2u(W[2],  A.z, a2); a3 = fdot2u(W[3],  A.w, a3);
    a0 = fdot2u(W[4],  B.x, a0); a1 = fdot2u(W[5],  B.y, a1);
    a2 = fdot2u(W[6],  B.z, a2); a3 = fdot2u(W[7],  B.w, a3);
    a0 = fdot2u(W[8],  C.x, a0); a1 = fdot2u(W[9],  C.y, a1);
    a2 = fdot2u(W[10], C.z, a2); a3 = fdot2u(W[11], C.w, a3);
    a0 = fdot2u(W[12], D.x, a0); a1 = fdot2u(W[13], D.y, a1);
    a2 = fdot2u(W[14], D.z, a2); a3 = fdot2u(W[15], D.w, a3);
    return s + ((a0 + a1) + (a2 + a3));
}

// ---------------------------------------------------------------------------
// Kernel 0: cast W_ih fp32 -> fp16 (tiny, one-time)
// ---------------------------------------------------------------------------
__global__ void cast_wih(const float* __restrict__ w, _Float16* __restrict__ o, int n) {
    int i = blockIdx.x * blockDim.x + threadIdx.x;
    if (i < n) o[i] = (_Float16)w[i];
}

// ---------------------------------------------------------------------------
// Kernel 1: gi = x @ W_ih^T + b_ih, stored fp16 [B*T][768]
// Per-wave 64x64 C tile, K=256, no LDS. MFMA f32_16x16x32_f16.
// ---------------------------------------------------------------------------
__global__ void gi_gemm(const float* __restrict__ x, const _Float16* __restrict__ wih,
                        const float* __restrict__ bih, _Float16* __restrict__ gi) {
    const int lane = threadIdx.x & 63;
    const int wid  = threadIdx.x >> 6;
    const int gt   = blockIdx.x * 4 + wid;       // wave-tile id, n fastest
    const int nt   = gt % 12;
    const int mt   = gt / 12;
    const int m0   = mt * 64;
    const int n0   = nt * 64;
    const int lr   = lane & 15;
    const int kg   = (lane >> 4) * 8;

    f4 acc[4][4] = {};

    #pragma unroll
    for (int kk = 0; kk < 256; kk += 32) {
        h8 af[4];
        h8 bf[4];
        #pragma unroll
        for (int m = 0; m < 4; ++m) {
            const float* ap = x + (size_t)(m0 + m * 16 + lr) * 256 + kk + kg;
            f4 lo = *(const f4*)ap;
            f4 hi = *(const f4*)(ap + 4);
            uint4 uu;
            uu.x = pk2(lo.x, lo.y);
            uu.y = pk2(lo.z, lo.w);
            uu.z = pk2(hi.x, hi.y);
            uu.w = pk2(hi.z, hi.w);
            af[m] = __builtin_bit_cast(h8, uu);
        }
        #pragma unroll
        for (int n = 0; n < 4; ++n) {
            bf[n] = *(const h8*)(wih + (size_t)(n0 + n * 16 + lr) * 256 + kk + kg);
        }
        #pragma unroll
        for (int m = 0; m < 4; ++m) {
            #pragma unroll
            for (int n = 0; n < 4; ++n) {
                acc[m][n] = __builtin_amdgcn_mfma_f32_16x16x32_f16(af[m], bf[n], acc[m][n], 0, 0, 0);
            }
        }
    }

    const int rg = (lane >> 4) * 4;
    #pragma unroll
    for (int n = 0; n < 4; ++n) {
        const int col = n0 + n * 16 + lr;
        const float bv = bih[col];
        #pragma unroll
        for (int m = 0; m < 4; ++m) {
            #pragma unroll
            for (int r = 0; r < 4; ++r) {
                const int row = m0 + m * 16 + rg + r;
                gi[(size_t)row * G3 + col] = (_Float16)(acc[m][n][r] + bv);
            }
        }
    }
}

// ---------------------------------------------------------------------------
// Kernel 2: sequential GRU scan. One workgroup per batch element.
// 512 threads = (rgrp = tid>>1) x (sub = tid&1). Thread owns rows
// rgrp*3 + j (j=0..2), columns [sub*128, sub*128+128) of W_hh:
// 3 x 4 uv16 = 192 packed-f16x2 regs as named SSA values.
// __launch_bounds__(512, 2): 2nd arg = MIN WAVES PER EU -> 256-VGPR
// budget (the amdgpu_waves_per_eu attribute was ignored in R7: VGPR=128,
// spill). Static pressure ~245 < 256.
// Per step: 4 q-blocks of {4 x b128 h-read, 3 rows x 16 fdot2},
// 2-lane ds_swizzle reduce, gate math in threads 0..255 (h in reg).
// n-gate bias is r-gated: n = tanh(i_n + r*(dot_n + b_hn)).
// ---------------------------------------------------------------------------
__global__ __launch_bounds__(512, 2)
void gru_scan(
        const _Float16* __restrict__ gi, const float* __restrict__ whh,
        const float* __restrict__ bhh, float* __restrict__ out) {
    __shared__ alignas(16) unsigned int hpk[128];  // h as packed f16x2
    __shared__ float ghl[768];                     // raw h-side dot sums

    const int b     = blockIdx.x;
    const int tid   = threadIdx.x;
    const int sub   = tid & 1;
    const int rbase = (tid >> 1) * 3;

    auto loadw = [&](int j, int q) -> uv16 {
        const f4* wp = (const f4*)(whh + (size_t)(rbase + j) * 256 + sub * 128 + q * 32);
        uv16 W;
        #pragma unroll
        for (int i = 0; i < 8; ++i) {
            f4 v = wp[i];
            W[2 * i]     = pk2(v.x, v.y);
            W[2 * i + 1] = pk2(v.z, v.w);
        }
        return W;
    };
    const uv16 w00 = loadw(0,0), w01 = loadw(0,1), w02 = loadw(0,2), w03 = loadw(0,3);
    const uv16 w10 = loadw(1,0), w11 = loadw(1,1), w12 = loadw(1,2), w13 = loadw(1,3);
    const uv16 w20 = loadw(2,0), w21 = loadw(2,1), w22 = loadw(2,2), w23 = loadw(2,3);

    if (tid < 128) hpk[tid] = 0u;

    // gate-math threads: bias + 2-deep gi prefetch
    const _Float16* gb = gi + (size_t)b * TT * G3;
    float b_r = 0.f, b_z = 0.f, b_n = 0.f;
    float c_r = 0.f, c_z = 0.f, c_n = 0.f;   // step t
    float n_r = 0.f, n_z = 0.f, n_n = 0.f;   // step t+1
    float hcur = 0.f;
    if (tid < 256) {
        b_r = bhh[tid];
        b_z = bhh[256 + tid];
        b_n = bhh[512 + tid];
        c_r = (float)gb[tid];
        c_z = (float)gb[256 + tid];
        c_n = (float)gb[512 + tid];
        n_r = (float)gb[G3 + tid];
        n_z = (float)gb[G3 + 256 + tid];
        n_n = (float)gb[G3 + 512 + tid];
    }
    __syncthreads();

    for (int t = 0; t < TT; ++t) {
        // issue loads for step t+2 (consumed ~2 steps later)
        float p_r = 0.f, p_z = 0.f, p_n = 0.f;
        if (tid < 256 && t + 2 < TT) {
            const _Float16* g2 = gb + (size_t)(t + 2) * G3;
            p_r = (float)g2[tid];
            p_z = (float)g2[256 + tid];
            p_n = (float)g2[512 + tid];
        }

        float s0 = 0.f, s1 = 0.f, s2 = 0.f;
        #define QBLOCK(q, W0, W1, W2)                                         \
        {                                                                     \
            const uint4* hp = (const uint4*)&hpk[sub * 64 + (q) * 16];        \
            const uint4 A = hp[0], B = hp[1], C = hp[2], D = hp[3];           \
            s0 = dot16(W0, A, B, C, D, s0);                                   \
            s1 = dot16(W1, A, B, C, D, s1);                                   \
            s2 = dot16(W2, A, B, C, D, s2);                                   \
        }
        QBLOCK(0, w00, w10, w20)
        QBLOCK(1, w01, w11, w21)
        QBLOCK(2, w02, w12, w22)
        QBLOCK(3, w03, w13, w23)
        #undef QBLOCK

        // 2-lane butterfly (xor 1) reduces the two column halves
        s0 = swz_add<0x041F>(s0);
        s1 = swz_add<0x041F>(s1);
        s2 = swz_add<0x041F>(s2);
        if (sub == 0) {
            ghl[rbase + 0] = s0;
            ghl[rbase + 1] = s1;
            ghl[rbase + 2] = s2;
        }
        __syncthreads();

        if (tid < 256) {
            const float xr = c_r + b_r + ghl[tid];
            const float xz = c_z + b_z + ghl[256 + tid];
            const float r = __builtin_amdgcn_rcpf(1.f + __expf(-xr));
            const float z = __builtin_amdgcn_rcpf(1.f + __expf(-xz));
            // b_hn must be r-gated: n = tanh(i_n + r*(dot_n + b_hn))
            const float xn = c_n + r * (ghl[512 + tid] + b_n);
            const float th = 1.f - 2.f * __builtin_amdgcn_rcpf(__expf(2.f * xn) + 1.f);
            hcur = (1.f - z) * th + z * hcur;
            ((_Float16*)hpk)[tid] = (_Float16)hcur;
            c_r = n_r; c_z = n_z; c_n = n_n;
            n_r = p_r; n_z = p_z; n_n = p_n;
        }
        __syncthreads();
    }

    if (tid < 256) out[(size_t)b * HH + tid] = hcur;
}

// ---------------------------------------------------------------------------
extern "C" void kernel_launch(void* const* d_in, const int* in_sizes, int n_in,
                              void* d_out, int out_size, void* d_ws, size_t ws_size,
                              hipStream_t stream) {
    const float* x   = (const float*)d_in[0];
    const float* wih = (const float*)d_in[1];
    const float* whh = (const float*)d_in[2];
    const float* bih = (const float*)d_in[3];
    const float* bhh = (const float*)d_in[4];
    float* out = (float*)d_out;

    // workspace: [0, 384KB) W_ih fp16 ; [512KB, 512KB+192MB) gi fp16
    _Float16* wih_h = (_Float16*)d_ws;
    _Float16* gi    = (_Float16*)((char*)d_ws + 512 * 1024);

    cast_wih<<<768, 256, 0, stream>>>(wih, wih_h, G3 * II);
    gi_gemm<<<6144, 256, 0, stream>>>(x, wih_h, bih, gi);
    gru_scan<<<BB, 512, 0, stream>>>(gi, whh, bhh, out);
}